// Round 1
// baseline (856.791 us; speedup 1.0000x reference)
//
#include <hip/hip_runtime.h>
#include <math.h>

#define BN_   2048
#define INDIM 1024
#define HD    256
#define OD    512
#define TN    12
#define KN    3
#define NHOPS 4
#define TP1   13

#define ROWS  16
#define KC    16

// ---------------- init ----------------
__global__ __launch_bounds__(256) void k_init(const int* __restrict__ init_t,
                                              int* __restrict__ tempers,
                                              int* __restrict__ done) {
  int n = blockIdx.x * 256 + threadIdx.x;
  if (n < BN_) { tempers[n] = init_t[n]; done[n] = 0; }
}

// ---------------- per-hop grouping: histogram + scan + scatter (one block) ----------------
__global__ __launch_bounds__(1024) void k_prep(int hop,
                                               const int* __restrict__ tempers,
                                               const int* __restrict__ done,
                                               int* __restrict__ counts,
                                               int* __restrict__ offsets,
                                               int* __restrict__ gidx) {
  __shared__ int cnt[TN];
  __shared__ int offs[TN];
  __shared__ int cur[TN];
  int tid = threadIdx.x;
  if (tid < TN) cnt[tid] = 0;
  __syncthreads();
  for (int n = tid; n < BN_; n += 1024)
    if (!done[n]) atomicAdd(&cnt[tempers[n]], 1);
  __syncthreads();
  if (tid == 0) {
    int run = 0;
    for (int t = 0; t < TN; ++t) { offs[t] = run; run += cnt[t]; }
  }
  __syncthreads();
  if (tid < TN) {
    counts[hop * 16 + tid]  = cnt[tid];
    offsets[hop * 16 + tid] = offs[tid];
    cur[tid] = offs[tid];
  }
  __syncthreads();
  for (int n = tid; n < BN_; n += 1024)
    if (!done[n]) { int p = atomicAdd(&cur[tempers[n]], 1); gidx[p] = n; }
}

// ---------------- generic f32 tiled GEMM with bias: C = A@W + bias ----------------
template<int BM, int BNt, int BK, int TM, int TNt>
__global__ __launch_bounds__(256) void k_gemm_bias(const float* __restrict__ A,
                                                   const float* __restrict__ W,
                                                   const float* __restrict__ bias,
                                                   float* __restrict__ C,
                                                   int M, int N, int Kd) {
  __shared__ float sA[BM][BK + 4];
  __shared__ float sB[BK][BNt];
  const int tid = threadIdx.x;
  constexpr int CG = BNt / TNt;           // col groups
  const int tx = tid % CG;
  const int ty = tid / CG;
  const int bm = blockIdx.x * BM;
  const int bn = blockIdx.y * BNt;

  float acc[TM][TNt];
#pragma unroll
  for (int i = 0; i < TM; ++i)
#pragma unroll
    for (int j = 0; j < TNt; ++j) acc[i][j] = 0.f;

  constexpr int A4 = BM * BK / 4;   // float4 count
  constexpr int B4 = BK * BNt / 4;

  for (int kc = 0; kc < Kd; kc += BK) {
    __syncthreads();
#pragma unroll
    for (int l = 0; l < A4 / 256; ++l) {
      int idx = tid + l * 256;
      int r = idx / (BK / 4);
      int c = (idx % (BK / 4)) * 4;
      *(float4*)&sA[r][c] = *(const float4*)&A[(size_t)(bm + r) * Kd + kc + c];
    }
#pragma unroll
    for (int l = 0; l < B4 / 256; ++l) {
      int idx = tid + l * 256;
      int r = idx / (BNt / 4);
      int c = (idx % (BNt / 4)) * 4;
      *(float4*)&sB[r][c] = *(const float4*)&W[(size_t)(kc + r) * N + bn + c];
    }
    __syncthreads();
#pragma unroll
    for (int kk = 0; kk < BK; ++kk) {
      float a[TM];
#pragma unroll
      for (int i = 0; i < TM; ++i) a[i] = sA[ty * TM + i][kk];
      float b[TNt];
      *(float4*)&b[0] = *(const float4*)&sB[kk][tx * TNt];
#pragma unroll
      for (int i = 0; i < TM; ++i)
#pragma unroll
        for (int j = 0; j < TNt; ++j) acc[i][j] = fmaf(a[i], b[j], acc[i][j]);
    }
  }
#pragma unroll
  for (int i = 0; i < TM; ++i)
#pragma unroll
    for (int j = 0; j < TNt; ++j)
      C[(size_t)(bm + ty * TM + i) * N + bn + tx * TNt + j] =
          acc[i][j] + bias[bn + tx * TNt + j];
}

// ---------------- expert tile GEMM helper: acc += S(16x256) @ W(256x256), K-chunked ----------------
__device__ __forceinline__ void tile_gemm(const float (*S)[HD],
                                          const float* __restrict__ W,
                                          float (*sB)[HD],
                                          float acc[2][8],
                                          int tid, int tx, int ty) {
  for (int kc = 0; kc < HD; kc += KC) {
    __syncthreads();
#pragma unroll
    for (int l = 0; l < (KC * HD / 4) / 256; ++l) {   // 4 float4 per thread
      int idx = tid + l * 256;
      int r = idx >> 6;              // 64 float4 per row
      int c = (idx & 63) << 2;
      *(float4*)&sB[r][c] = *(const float4*)&W[(size_t)(kc + r) * HD + c];
    }
    __syncthreads();
#pragma unroll
    for (int kk = 0; kk < KC; ++kk) {
      float bv[8];
      *(float4*)&bv[0] = *(const float4*)&sB[kk][tx * 8];
      *(float4*)&bv[4] = *(const float4*)&sB[kk][tx * 8 + 4];
      float a0 = S[ty * 2 + 0][kc + kk];
      float a1 = S[ty * 2 + 1][kc + kk];
#pragma unroll
      for (int j = 0; j < 8; ++j) {
        acc[0][j] = fmaf(a0, bv[j], acc[0][j]);
        acc[1][j] = fmaf(a1, bv[j], acc[1][j]);
      }
    }
  }
}

// ---------------- per-hop expert MLP + routing ----------------
__global__ __launch_bounds__(256) void k_expert(
    int hop,
    const float* __restrict__ W1, const float* __restrict__ b1,
    const float* __restrict__ W2, const float* __restrict__ b2,
    const float* __restrict__ Wr, const float* __restrict__ br,
    const float* __restrict__ op_noise, const float* __restrict__ route_u,
    const int* __restrict__ counts, const int* __restrict__ offsets,
    const int* __restrict__ gidx,
    float* __restrict__ states, int* __restrict__ tempers, int* __restrict__ done) {
  const int bid = blockIdx.x;
  const int t  = bid % TN;       // temper fastest -> spreads tempers across XCD round-robin classes
  const int rb = bid / TN;
  const int cnt = counts[hop * 16 + t];
  const int r0 = rb * ROWS;
  if (r0 >= cnt) return;
  const int base = offsets[hop * 16 + t] + r0;
  const int rows = min(ROWS, cnt - r0);

  __shared__ float sA[ROWS][HD];     // gathered input states (16 KB)
  __shared__ float sH[ROWS][HD];     // h1 / out staging     (16 KB)
  __shared__ float sB[KC][HD];       // weight K-chunk       (16 KB), reused for Wr (3328 f)
  __shared__ float sL[ROWS][TP1 + 3];
  __shared__ int   sN[ROWS];

  const int tid = threadIdx.x;
  const int tx = tid & 31;           // cols tx*8 .. tx*8+7
  const int ty = tid >> 5;           // rows ty*2, ty*2+1

  if (tid < ROWS) sN[tid] = (tid < rows) ? gidx[base + tid] : 0;

  // gather states rows -> sA (zero-fill tail rows)
#pragma unroll
  for (int l = 0; l < 4; ++l) {
    int idx = tid + l * 256;
    int r = idx >> 6;
    int c = (idx & 63) << 2;
    float4 v = make_float4(0.f, 0.f, 0.f, 0.f);
    if (r < rows) {
      int n = gidx[base + r];
      v = *(const float4*)&states[(size_t)n * HD + c];
    }
    *(float4*)&sA[r][c] = v;
  }

  // softmax op-mixing weights for this (hop, temper)
  float wk[KN];
  {
    const float* on = op_noise + (hop * TN + t) * KN;
    float x0 = on[0], x1 = on[1], x2 = on[2];
    float m = fmaxf(fmaxf(x0, x1), x2);
    float e0 = expf(x0 - m), e1 = expf(x1 - m), e2 = expf(x2 - m);
    float inv = 1.f / (e0 + e1 + e2);
    wk[0] = e0 * inv; wk[1] = e1 * inv; wk[2] = e2 * inv;
  }

  float accO[2][8];
#pragma unroll
  for (int i = 0; i < 2; ++i)
#pragma unroll
    for (int j = 0; j < 8; ++j) accO[i][j] = 0.f;

  for (int k = 0; k < KN; ++k) {
    const float* Wa = W1 + (size_t)(t * KN + k) * HD * HD;
    const float* ba = b1 + (t * KN + k) * HD;
    const float* Wb = W2 + (size_t)(t * KN + k) * HD * HD;
    const float* bb = b2 + (t * KN + k) * HD;

    // h1 = relu(sA @ Wa + ba)
    float acc[2][8];
#pragma unroll
    for (int i = 0; i < 2; ++i)
#pragma unroll
      for (int j = 0; j < 8; ++j) acc[i][j] = 0.f;
    tile_gemm(sA, Wa, sB, acc, tid, tx, ty);

    __syncthreads();   // everyone done reading sB/sH before sH overwrite
#pragma unroll
    for (int i = 0; i < 2; ++i) {
      int r = ty * 2 + i;
      float4 v0, v1;
      v0.x = fmaxf(acc[i][0] + ba[tx * 8 + 0], 0.f);
      v0.y = fmaxf(acc[i][1] + ba[tx * 8 + 1], 0.f);
      v0.z = fmaxf(acc[i][2] + ba[tx * 8 + 2], 0.f);
      v0.w = fmaxf(acc[i][3] + ba[tx * 8 + 3], 0.f);
      v1.x = fmaxf(acc[i][4] + ba[tx * 8 + 4], 0.f);
      v1.y = fmaxf(acc[i][5] + ba[tx * 8 + 5], 0.f);
      v1.z = fmaxf(acc[i][6] + ba[tx * 8 + 6], 0.f);
      v1.w = fmaxf(acc[i][7] + ba[tx * 8 + 7], 0.f);
      *(float4*)&sH[r][tx * 8]     = v0;
      *(float4*)&sH[r][tx * 8 + 4] = v1;
    }

    // h2 = relu(sH @ Wb + bb); accO += wk * h2
#pragma unroll
    for (int i = 0; i < 2; ++i)
#pragma unroll
      for (int j = 0; j < 8; ++j) acc[i][j] = 0.f;
    tile_gemm(sH, Wb, sB, acc, tid, tx, ty);

#pragma unroll
    for (int i = 0; i < 2; ++i)
#pragma unroll
      for (int j = 0; j < 8; ++j)
        accO[i][j] = fmaf(wk[k], fmaxf(acc[i][j] + bb[tx * 8 + j], 0.f), accO[i][j]);
  }

  // out -> sH (for routing head)
  __syncthreads();
#pragma unroll
  for (int i = 0; i < 2; ++i) {
    int r = ty * 2 + i;
    float4 v0 = make_float4(accO[i][0], accO[i][1], accO[i][2], accO[i][3]);
    float4 v1 = make_float4(accO[i][4], accO[i][5], accO[i][6], accO[i][7]);
    *(float4*)&sH[r][tx * 8]     = v0;
    *(float4*)&sH[r][tx * 8 + 4] = v1;
  }
  // Wr -> sB region (3328 floats <= 4096)
  {
    float* sWr = (float*)sB;
    for (int idx = tid; idx < HD * TP1; idx += 256)
      sWr[idx] = Wr[(size_t)t * HD * TP1 + idx];
  }
  __syncthreads();

  // logits + gumbel: one thread per (row, gate)
  if (tid < ROWS * TP1) {
    int r = tid / TP1, g = tid - r * TP1;
    if (r < rows) {
      int n = sN[r];
      const float* sWr = (const float*)sB;
      float a = br[t * TP1 + g];
#pragma unroll 8
      for (int f = 0; f < HD; ++f) a = fmaf(sH[r][f], sWr[f * TP1 + g], a);
      float u = route_u[((size_t)hop * BN_ + n) * TP1 + g];
      float gb = -logf(-logf(u + 1e-9f) + 1e-9f);
      sL[r][g] = a + gb;
    }
  }
  __syncthreads();

  // first-occurrence argmax per row; update temper/done
  if (tid < rows) {
    int r = tid;
    float best = sL[r][0];
    int bj = 0;
#pragma unroll
    for (int g = 1; g < TP1; ++g) {
      float v = sL[r][g];
      if (v > best) { best = v; bj = g; }
    }
    int n = sN[r];
    tempers[n] = (bj >= TN) ? (TN - 1) : bj;   // min(sampled, T-1)
    if (bj == TN) done[n] = 1;                 // active & sampled==T
  }

  // write updated states (all grouped rows are active)
#pragma unroll
  for (int i = 0; i < 2; ++i) {
    int r = ty * 2 + i;
    if (r < rows) {
      int n = sN[r];
      float4 v0 = make_float4(accO[i][0], accO[i][1], accO[i][2], accO[i][3]);
      float4 v1 = make_float4(accO[i][4], accO[i][5], accO[i][6], accO[i][7]);
      *(float4*)&states[(size_t)n * HD + tx * 8]     = v0;
      *(float4*)&states[(size_t)n * HD + tx * 8 + 4] = v1;
    }
  }
}

// ---------------- launcher ----------------
extern "C" void kernel_launch(void* const* d_in, const int* in_sizes, int n_in,
                              void* d_out, int out_size, void* d_ws, size_t ws_size,
                              hipStream_t stream) {
  const float* x        = (const float*)d_in[0];
  const int*   init_t   = (const int*)d_in[1];
  const float* op_noise = (const float*)d_in[2];
  const float* route_u  = (const float*)d_in[3];
  const float* W_in     = (const float*)d_in[4];
  const float* b_in     = (const float*)d_in[5];
  const float* W1       = (const float*)d_in[6];
  const float* b1       = (const float*)d_in[7];
  const float* W2       = (const float*)d_in[8];
  const float* b2       = (const float*)d_in[9];
  const float* Wr       = (const float*)d_in[10];
  const float* br       = (const float*)d_in[11];
  const float* W_out    = (const float*)d_in[12];
  const float* b_out    = (const float*)d_in[13];
  float* out = (float*)d_out;

  float* states = (float*)d_ws;
  int* ib      = (int*)((char*)d_ws + (size_t)BN_ * HD * sizeof(float));
  int* tempers = ib;
  int* done    = ib + BN_;
  int* counts  = ib + 2 * BN_;
  int* offsets = counts + NHOPS * 16;
  int* gidx    = offsets + NHOPS * 16;

  k_init<<<(BN_ + 255) / 256, 256, 0, stream>>>(init_t, tempers, done);

  k_gemm_bias<64, 32, 32, 2, 4><<<dim3(BN_ / 64, HD / 32), 256, 0, stream>>>(
      x, W_in, b_in, states, BN_, HD, INDIM);

  for (int hop = 0; hop < NHOPS; ++hop) {
    k_prep<<<1, 1024, 0, stream>>>(hop, tempers, done, counts, offsets, gidx);
    k_expert<<<TN * (BN_ / ROWS), 256, 0, stream>>>(
        hop, W1, b1, W2, b2, Wr, br, op_noise, route_u,
        counts, offsets, gidx, states, tempers, done);
  }

  k_gemm_bias<64, 32, 32, 2, 4><<<dim3(BN_ / 64, OD / 32), 256, 0, stream>>>(
      states, W_out, b_out, out, BN_, OD, HD);
}

// Round 2
// 401.111 us; speedup vs baseline: 2.1360x; 2.1360x over previous
//
#include <hip/hip_runtime.h>
#include <math.h>

#define BN_   2048
#define INDIM 1024
#define HD    256
#define OD    512
#define TN    12
#define KN    3
#define NHOPS 4
#define TP1   13

#define ROWS  16
#define RBLK  (BN_ / ROWS)   // 128
#define KC    16

// async global -> LDS, 16B per lane (dest must be wave-uniform base + lane*16)
__device__ __forceinline__ void gll16(const float* g, float* l) {
  __builtin_amdgcn_global_load_lds(
      (const __attribute__((address_space(1))) void*)g,
      (__attribute__((address_space(3))) void*)l, 16, 0, 0);
}

// ---------------- init ----------------
__global__ __launch_bounds__(256) void k_init(const int* __restrict__ init_t,
                                              int* __restrict__ tempers,
                                              int* __restrict__ done) {
  int n = blockIdx.x * 256 + threadIdx.x;
  if (n < BN_) { tempers[n] = init_t[n]; done[n] = 0; }
}

// ---------------- per-hop grouping ----------------
__global__ __launch_bounds__(1024) void k_prep(int hop,
                                               const int* __restrict__ tempers,
                                               const int* __restrict__ done,
                                               int* __restrict__ counts,
                                               int* __restrict__ offsets,
                                               int* __restrict__ gidx) {
  __shared__ int cnt[TN];
  __shared__ int offs[TN];
  __shared__ int cur[TN];
  int tid = threadIdx.x;
  if (tid < TN) cnt[tid] = 0;
  __syncthreads();
  for (int n = tid; n < BN_; n += 1024)
    if (!done[n]) atomicAdd(&cnt[tempers[n]], 1);
  __syncthreads();
  if (tid == 0) {
    int run = 0;
    for (int t = 0; t < TN; ++t) { offs[t] = run; run += cnt[t]; }
  }
  __syncthreads();
  if (tid < TN) {
    counts[hop * 16 + tid]  = cnt[tid];
    offsets[hop * 16 + tid] = offs[tid];
    cur[tid] = offs[tid];
  }
  __syncthreads();
  for (int n = tid; n < BN_; n += 1024)
    if (!done[n]) { int p = atomicAdd(&cur[tempers[n]], 1); gidx[p] = n; }
}

// ---------------- generic f32 tiled GEMM with bias ----------------
template<int BM, int BNt, int BK, int TM, int TNt>
__global__ __launch_bounds__(256) void k_gemm_bias(const float* __restrict__ A,
                                                   const float* __restrict__ W,
                                                   const float* __restrict__ bias,
                                                   float* __restrict__ C,
                                                   int M, int N, int Kd) {
  __shared__ float sA[BM][BK + 4];
  __shared__ float sB[BK][BNt];
  const int tid = threadIdx.x;
  constexpr int CG = BNt / TNt;
  const int tx = tid % CG;
  const int ty = tid / CG;
  const int bm = blockIdx.x * BM;
  const int bn = blockIdx.y * BNt;

  float acc[TM][TNt];
#pragma unroll
  for (int i = 0; i < TM; ++i)
#pragma unroll
    for (int j = 0; j < TNt; ++j) acc[i][j] = 0.f;

  constexpr int A4 = BM * BK / 4;
  constexpr int B4 = BK * BNt / 4;

  for (int kc = 0; kc < Kd; kc += BK) {
    __syncthreads();
#pragma unroll
    for (int l = 0; l < A4 / 256; ++l) {
      int idx = tid + l * 256;
      int r = idx / (BK / 4);
      int c = (idx % (BK / 4)) * 4;
      *(float4*)&sA[r][c] = *(const float4*)&A[(size_t)(bm + r) * Kd + kc + c];
    }
#pragma unroll
    for (int l = 0; l < B4 / 256; ++l) {
      int idx = tid + l * 256;
      int r = idx / (BNt / 4);
      int c = (idx % (BNt / 4)) * 4;
      *(float4*)&sB[r][c] = *(const float4*)&W[(size_t)(kc + r) * N + bn + c];
    }
    __syncthreads();
#pragma unroll
    for (int kk = 0; kk < BK; ++kk) {
      float a[TM];
#pragma unroll
      for (int i = 0; i < TM; ++i) a[i] = sA[ty * TM + i][kk];
      float b[TNt];
      *(float4*)&b[0] = *(const float4*)&sB[kk][tx * TNt];
#pragma unroll
      for (int i = 0; i < TM; ++i)
#pragma unroll
        for (int j = 0; j < TNt; ++j) acc[i][j] = fmaf(a[i], b[j], acc[i][j]);
    }
  }
#pragma unroll
  for (int i = 0; i < TM; ++i)
#pragma unroll
    for (int j = 0; j < TNt; ++j)
      C[(size_t)(bm + ty * TM + i) * N + bn + tx * TNt + j] =
          acc[i][j] + bias[bn + tx * TNt + j];
}

// ---------------- phase A: h1 = relu(S @ W1[t,k] + b1[t,k]) ----------------
// grid = (TN*RBLK, KN); block 256. thread: tx=tid&63 -> 4 cols, ty=tid>>6 -> 4 rows
__global__ __launch_bounds__(256) void k_h1(
    int hop,
    const float* __restrict__ W1, const float* __restrict__ b1,
    const int* __restrict__ counts, const int* __restrict__ offsets,
    const int* __restrict__ gidx,
    const float* __restrict__ states, float* __restrict__ h1s) {
  const int t  = blockIdx.x % TN;
  const int rb = blockIdx.x / TN;
  const int k  = blockIdx.y;
  const int cnt = counts[hop * 16 + t];
  const int r0 = rb * ROWS;
  if (r0 >= cnt) return;
  const int base = offsets[hop * 16 + t] + r0;
  const int rows = min(ROWS, cnt - r0);

  __shared__ float sA[ROWS][HD];       // 16 KB
  __shared__ float sB[2][KC][HD];      // 32 KB

  const int tid = threadIdx.x;
  const int tx = tid & 63;             // cols tx*4..+3
  const int ty = tid >> 6;             // rows ty*4..+3

  const float* Wk = W1 + (size_t)(t * KN + k) * HD * HD;

  // gather states rows -> sA (async; tail rows left stale, discarded)
#pragma unroll
  for (int l = 0; l < 4; ++l) {
    int idx = tid + l * 256;
    int r = idx >> 6;                  // wave-uniform
    int c = (idx & 63) << 2;
    if (r < rows) {
      int n = gidx[base + r];
      gll16(&states[(size_t)n * HD + c], &sA[r][c]);
    }
  }
  // stage W chunk 0
#pragma unroll
  for (int l = 0; l < 4; ++l) {
    int idx = tid + l * 256;
    int r = idx >> 6;
    int c = (idx & 63) << 2;
    gll16(&Wk[(size_t)r * HD + c], &sB[0][r][c]);
  }

  float acc[4][4];
#pragma unroll
  for (int i = 0; i < 4; ++i)
#pragma unroll
    for (int j = 0; j < 4; ++j) acc[i][j] = 0.f;

  for (int cchunk = 0; cchunk < HD / KC; ++cchunk) {
    __syncthreads();                   // chunk data ready + prev compute done
    int cur = cchunk & 1;
    if (cchunk + 1 < HD / KC) {
      const float* Wn = Wk + (size_t)(cchunk + 1) * KC * HD;
#pragma unroll
      for (int l = 0; l < 4; ++l) {
        int idx = tid + l * 256;
        int r = idx >> 6;
        int c = (idx & 63) << 2;
        gll16(&Wn[(size_t)r * HD + c], &sB[cur ^ 1][r][c]);
      }
    }
    int kc = cchunk * KC;
#pragma unroll
    for (int kk = 0; kk < KC; ++kk) {
      float bv[4];
      *(float4*)&bv[0] = *(const float4*)&sB[cur][kk][tx * 4];
#pragma unroll
      for (int i = 0; i < 4; ++i) {
        float a = sA[ty * 4 + i][kc + kk];
        acc[i][0] = fmaf(a, bv[0], acc[i][0]);
        acc[i][1] = fmaf(a, bv[1], acc[i][1]);
        acc[i][2] = fmaf(a, bv[2], acc[i][2]);
        acc[i][3] = fmaf(a, bv[3], acc[i][3]);
      }
    }
  }

  const float* bk = b1 + (t * KN + k) * HD;
  float bb[4];
  *(float4*)&bb[0] = *(const float4*)&bk[tx * 4];
#pragma unroll
  for (int i = 0; i < 4; ++i) {
    int r = ty * 4 + i;
    if (r < rows) {
      float4 o;
      o.x = fmaxf(acc[i][0] + bb[0], 0.f);
      o.y = fmaxf(acc[i][1] + bb[1], 0.f);
      o.z = fmaxf(acc[i][2] + bb[2], 0.f);
      o.w = fmaxf(acc[i][3] + bb[3], 0.f);
      *(float4*)&h1s[((size_t)(base + r) * KN + k) * HD + tx * 4] = o;
    }
  }
}

// ---------------- phase B: states = sum_k wk * relu(h1 @ W2 + b2) ----------------
// grid = (TN*RBLK, 2 col halves); block 256. thread: tx=tid&31 -> 4 cols, ty=tid>>5 -> 2 rows
__global__ __launch_bounds__(256) void k_h2(
    int hop,
    const float* __restrict__ W2, const float* __restrict__ b2,
    const float* __restrict__ op_noise,
    const int* __restrict__ counts, const int* __restrict__ offsets,
    const int* __restrict__ gidx,
    const float* __restrict__ h1s, float* __restrict__ states) {
  const int t  = blockIdx.x % TN;
  const int rb = blockIdx.x / TN;
  const int ch = blockIdx.y;           // column half: cols ch*128..+127
  const int cnt = counts[hop * 16 + t];
  const int r0 = rb * ROWS;
  if (r0 >= cnt) return;
  const int base = offsets[hop * 16 + t] + r0;
  const int rows = min(ROWS, cnt - r0);

  __shared__ float sA[ROWS][HD];       // h1 slice, 16 KB
  __shared__ float sB[2][KC][128];     // 16 KB

  const int tid = threadIdx.x;
  const int tx = tid & 31;             // cols ch*128 + tx*4..+3
  const int ty = tid >> 5;             // rows ty*2..+1

  // softmax op-mixing weights
  float wk[KN];
  {
    const float* on = op_noise + (hop * TN + t) * KN;
    float x0 = on[0], x1 = on[1], x2 = on[2];
    float m = fmaxf(fmaxf(x0, x1), x2);
    float e0 = expf(x0 - m), e1 = expf(x1 - m), e2 = expf(x2 - m);
    float inv = 1.f / (e0 + e1 + e2);
    wk[0] = e0 * inv; wk[1] = e1 * inv; wk[2] = e2 * inv;
  }

  float accO[2][4];
#pragma unroll
  for (int i = 0; i < 2; ++i)
#pragma unroll
    for (int j = 0; j < 4; ++j) accO[i][j] = 0.f;

  for (int k = 0; k < KN; ++k) {
    __syncthreads();                   // prev k compute done: safe to overwrite sA/sB
    const float* Wk = W2 + (size_t)(t * KN + k) * HD * HD + ch * 128;
    // stage h1 rows for this k
#pragma unroll
    for (int l = 0; l < 4; ++l) {
      int idx = tid + l * 256;
      int r = idx >> 6;                // wave-uniform
      int c = (idx & 63) << 2;
      if (r < rows)
        gll16(&h1s[((size_t)(base + r) * KN + k) * HD + c], &sA[r][c]);
    }
    // stage W chunk 0
#pragma unroll
    for (int l = 0; l < 2; ++l) {
      int idx = tid + l * 256;
      int r = idx >> 5;
      int c = (idx & 31) << 2;
      gll16(&Wk[(size_t)r * HD + c], &sB[0][r][c]);
    }

    float acc[2][4];
#pragma unroll
    for (int i = 0; i < 2; ++i)
#pragma unroll
      for (int j = 0; j < 4; ++j) acc[i][j] = 0.f;

    for (int cchunk = 0; cchunk < HD / KC; ++cchunk) {
      __syncthreads();
      int cur = cchunk & 1;
      if (cchunk + 1 < HD / KC) {
        const float* Wn = Wk + (size_t)(cchunk + 1) * KC * HD;
#pragma unroll
        for (int l = 0; l < 2; ++l) {
          int idx = tid + l * 256;
          int r = idx >> 5;
          int c = (idx & 31) << 2;
          gll16(&Wn[(size_t)r * HD + c], &sB[cur ^ 1][r][c]);
        }
      }
      int kc = cchunk * KC;
#pragma unroll
      for (int kk = 0; kk < KC; ++kk) {
        float bv[4];
        *(float4*)&bv[0] = *(const float4*)&sB[cur][kk][tx * 4];
        float a0 = sA[ty * 2 + 0][kc + kk];
        float a1 = sA[ty * 2 + 1][kc + kk];
#pragma unroll
        for (int j = 0; j < 4; ++j) {
          acc[0][j] = fmaf(a0, bv[j], acc[0][j]);
          acc[1][j] = fmaf(a1, bv[j], acc[1][j]);
        }
      }
    }

    const float* bbp = b2 + (t * KN + k) * HD + ch * 128;
    float bb[4];
    *(float4*)&bb[0] = *(const float4*)&bbp[tx * 4];
#pragma unroll
    for (int i = 0; i < 2; ++i)
#pragma unroll
      for (int j = 0; j < 4; ++j)
        accO[i][j] = fmaf(wk[k], fmaxf(acc[i][j] + bb[j], 0.f), accO[i][j]);
  }

  // write updated states
#pragma unroll
  for (int i = 0; i < 2; ++i) {
    int r = ty * 2 + i;
    if (r < rows) {
      int n = gidx[base + r];
      float4 o = make_float4(accO[i][0], accO[i][1], accO[i][2], accO[i][3]);
      *(float4*)&states[(size_t)n * HD + ch * 128 + tx * 4] = o;
    }
  }
}

// ---------------- phase C: routing head + Gumbel argmax + update ----------------
__global__ __launch_bounds__(256) void k_route(
    int hop,
    const float* __restrict__ Wr, const float* __restrict__ br,
    const float* __restrict__ route_u,
    const int* __restrict__ counts, const int* __restrict__ offsets,
    const int* __restrict__ gidx,
    const float* __restrict__ states,
    int* __restrict__ tempers, int* __restrict__ done) {
  const int t  = blockIdx.x % TN;
  const int rb = blockIdx.x / TN;
  const int cnt = counts[hop * 16 + t];
  const int r0 = rb * ROWS;
  if (r0 >= cnt) return;
  const int base = offsets[hop * 16 + t] + r0;
  const int rows = min(ROWS, cnt - r0);

  __shared__ float sO[ROWS][HD + 4];   // padded: distinct banks per row
  __shared__ float sWr[HD * TP1];
  __shared__ float sL[ROWS][16];
  __shared__ int   sN[ROWS];

  const int tid = threadIdx.x;
  if (tid < ROWS && tid < rows) sN[tid] = gidx[base + tid];

#pragma unroll
  for (int l = 0; l < 4; ++l) {
    int idx = tid + l * 256;
    int r = idx >> 6;
    int c = (idx & 63) << 2;
    if (r < rows)
      *(float4*)&sO[r][c] = *(const float4*)&states[(size_t)gidx[base + r] * HD + c];
  }
  for (int i = tid; i < HD * TP1; i += 256)
    sWr[i] = Wr[(size_t)t * HD * TP1 + i];
  __syncthreads();

  int r = tid >> 4, g = tid & 15;
  if (r < rows && g < TP1) {
    float a = br[t * TP1 + g];
#pragma unroll 8
    for (int f = 0; f < HD; ++f) a = fmaf(sO[r][f], sWr[f * TP1 + g], a);
    float u = route_u[((size_t)hop * BN_ + sN[r]) * TP1 + g];
    float gb = -logf(-logf(u + 1e-9f) + 1e-9f);
    sL[r][g] = a + gb;
  }
  __syncthreads();

  if (tid < rows) {
    float best = sL[tid][0];
    int bj = 0;
#pragma unroll
    for (int gg = 1; gg < TP1; ++gg) {
      float v = sL[tid][gg];
      if (v > best) { best = v; bj = gg; }
    }
    int n = sN[tid];
    tempers[n] = (bj >= TN) ? (TN - 1) : bj;
    if (bj == TN) done[n] = 1;
  }
}

// ---------------- launcher ----------------
extern "C" void kernel_launch(void* const* d_in, const int* in_sizes, int n_in,
                              void* d_out, int out_size, void* d_ws, size_t ws_size,
                              hipStream_t stream) {
  const float* x        = (const float*)d_in[0];
  const int*   init_t   = (const int*)d_in[1];
  const float* op_noise = (const float*)d_in[2];
  const float* route_u  = (const float*)d_in[3];
  const float* W_in     = (const float*)d_in[4];
  const float* b_in     = (const float*)d_in[5];
  const float* W1       = (const float*)d_in[6];
  const float* b1       = (const float*)d_in[7];
  const float* W2       = (const float*)d_in[8];
  const float* b2       = (const float*)d_in[9];
  const float* Wr       = (const float*)d_in[10];
  const float* br       = (const float*)d_in[11];
  const float* W_out    = (const float*)d_in[12];
  const float* b_out    = (const float*)d_in[13];
  float* out = (float*)d_out;

  float* states = (float*)d_ws;
  float* h1s    = states + (size_t)BN_ * HD;
  int* ib      = (int*)(h1s + (size_t)BN_ * KN * HD);
  int* tempers = ib;
  int* done    = ib + BN_;
  int* counts  = ib + 2 * BN_;
  int* offsets = counts + NHOPS * 16;
  int* gidx    = offsets + NHOPS * 16;

  k_init<<<(BN_ + 255) / 256, 256, 0, stream>>>(init_t, tempers, done);

  k_gemm_bias<64, 64, 32, 4, 4><<<dim3(BN_ / 64, HD / 64), 256, 0, stream>>>(
      x, W_in, b_in, states, BN_, HD, INDIM);

  for (int hop = 0; hop < NHOPS; ++hop) {
    k_prep<<<1, 1024, 0, stream>>>(hop, tempers, done, counts, offsets, gidx);
    k_h1<<<dim3(TN * RBLK, KN), 256, 0, stream>>>(
        hop, W1, b1, counts, offsets, gidx, states, h1s);
    k_h2<<<dim3(TN * RBLK, 2), 256, 0, stream>>>(
        hop, W2, b2, op_noise, counts, offsets, gidx, h1s, states);
    k_route<<<TN * RBLK, 256, 0, stream>>>(
        hop, Wr, br, route_u, counts, offsets, gidx, states, tempers, done);
  }

  k_gemm_bias<64, 64, 32, 4, 4><<<dim3(BN_ / 64, OD / 64), 256, 0, stream>>>(
      states, W_out, b_out, out, BN_, OD, HD);
}

// Round 3
// 355.592 us; speedup vs baseline: 2.4095x; 1.1280x over previous
//
#include <hip/hip_runtime.h>
#include <math.h>

#define BN_   2048
#define INDIM 1024
#define HD    256
#define OD    512
#define TN    12
#define KN    3
#define NHOPS 4
#define TP1   13

#define ROWS  16
#define RBLK  (BN_ / ROWS)   // 128

// async global -> LDS, 16B per lane (LDS dest must be linear in tid)
__device__ __forceinline__ void gll16(const float* g, float* l) {
  __builtin_amdgcn_global_load_lds(
      (const __attribute__((address_space(1))) void*)g,
      (__attribute__((address_space(3))) void*)l, 16, 0, 0);
}

#define VMW4() asm volatile("s_waitcnt vmcnt(4)" ::: "memory")
#define VMW3() asm volatile("s_waitcnt vmcnt(3)" ::: "memory")
#define VMW0() asm volatile("s_waitcnt vmcnt(0)" ::: "memory")
#define BAR()  do { __builtin_amdgcn_s_barrier(); asm volatile("" ::: "memory"); } while (0)

// ---------------- init ----------------
__global__ __launch_bounds__(256) void k_init(const int* __restrict__ init_t,
                                              int* __restrict__ tempers,
                                              int* __restrict__ done) {
  int n = blockIdx.x * 256 + threadIdx.x;
  if (n < BN_) { tempers[n] = init_t[n]; done[n] = 0; }
}

// ---------------- per-hop grouping ----------------
__global__ __launch_bounds__(1024) void k_prep(int hop,
                                               const int* __restrict__ tempers,
                                               const int* __restrict__ done,
                                               int* __restrict__ counts,
                                               int* __restrict__ offsets,
                                               int* __restrict__ gidx) {
  __shared__ int cnt[TN];
  __shared__ int offs[TN];
  __shared__ int cur[TN];
  int tid = threadIdx.x;
  if (tid < TN) cnt[tid] = 0;
  __syncthreads();
  for (int n = tid; n < BN_; n += 1024)
    if (!done[n]) atomicAdd(&cnt[tempers[n]], 1);
  __syncthreads();
  if (tid == 0) {
    int run = 0;
    for (int t = 0; t < TN; ++t) { offs[t] = run; run += cnt[t]; }
  }
  __syncthreads();
  if (tid < TN) {
    counts[hop * 16 + tid]  = cnt[tid];
    offsets[hop * 16 + tid] = offs[tid];
    cur[tid] = offs[tid];
  }
  __syncthreads();
  for (int n = tid; n < BN_; n += 1024)
    if (!done[n]) { int p = atomicAdd(&cur[tempers[n]], 1); gidx[p] = n; }
}

// ---------------- dense GEMM with bias: counted-vmcnt 2-phase pipeline ----------------
// BM=32, BN=64, BK=32; 256 thr; per-lane 4 rows x 2 cols.
__global__ __launch_bounds__(256) void k_gemm_bias(const float* __restrict__ A,
                                                   const float* __restrict__ W,
                                                   const float* __restrict__ bias,
                                                   float* __restrict__ C,
                                                   int M, int N, int Kd) {
  __shared__ __align__(16) float sA[2][32][32];   // 2 x 4KB
  __shared__ __align__(16) float sB[2][32][64];   // 2 x 8KB
  const int tid = threadIdx.x;
  const int tx = tid & 31;          // col group: cols tx*2..+1
  const int ty = tid >> 5;          // row group: rows ty*4..+3
  const int bm = blockIdx.x * 32;
  const int bn = blockIdx.y * 64;
  const int nch = Kd >> 5;

  // stage chunk `kc` into buffer `b`
#define GSTAGE(kcv, b)                                                        \
  do {                                                                        \
    int r_ = tid >> 3, c_ = (tid & 7) << 2;                                   \
    gll16(&A[(size_t)(bm + r_) * Kd + (kcv) + c_], &sA[b][r_][c_]);           \
    _Pragma("unroll")                                                         \
    for (int l_ = 0; l_ < 2; ++l_) {                                          \
      int idx_ = tid + l_ * 256;                                              \
      int rr_ = idx_ >> 4, cc_ = (idx_ & 15) << 2;                            \
      gll16(&W[(size_t)((kcv) + rr_) * N + bn + cc_], &sB[b][rr_][cc_]);      \
    }                                                                         \
  } while (0)

  float acc[4][2];
#pragma unroll
  for (int i = 0; i < 4; ++i) { acc[i][0] = 0.f; acc[i][1] = 0.f; }

  GSTAGE(0, 0);

#define GCOMP(cur)                                                            \
  do {                                                                        \
    _Pragma("unroll")                                                         \
    for (int k4 = 0; k4 < 8; ++k4) {                                          \
      float4 a4[4];                                                           \
      _Pragma("unroll")                                                       \
      for (int i = 0; i < 4; ++i)                                             \
        a4[i] = *(const float4*)&sA[cur][ty * 4 + i][k4 * 4];                 \
      _Pragma("unroll")                                                       \
      for (int u = 0; u < 4; ++u) {                                           \
        float2 bv = *(const float2*)&sB[cur][k4 * 4 + u][tx * 2];             \
        _Pragma("unroll")                                                     \
        for (int i = 0; i < 4; ++i) {                                         \
          float a = ((const float*)&a4[i])[u];                                \
          acc[i][0] = fmaf(a, bv.x, acc[i][0]);                               \
          acc[i][1] = fmaf(a, bv.y, acc[i][1]);                               \
        }                                                                     \
      }                                                                       \
    }                                                                         \
  } while (0)

#pragma unroll 1
  for (int ch = 0; ch < nch - 1; ++ch) {
    GSTAGE((ch + 1) << 5, (ch + 1) & 1);
    VMW3(); BAR();
    int cur = ch & 1;
    GCOMP(cur);
    BAR();
  }
  VMW0(); BAR();
  GCOMP((nch - 1) & 1);

  float2 bb = *(const float2*)&bias[bn + tx * 2];
#pragma unroll
  for (int i = 0; i < 4; ++i) {
    float2 o = make_float2(acc[i][0] + bb.x, acc[i][1] + bb.y);
    *(float2*)&C[(size_t)(bm + ty * 4 + i) * N + bn + tx * 2] = o;
  }
#undef GSTAGE
#undef GCOMP
}

// ---------------- fused expert: h1 = relu(S@W1+b1); part_k = wk*relu(h1@W2+b2) ----------------
// grid.x = 2048 (XCD-clustered temper decode), grid.y = KN. 256 thr.
// lane: tx=tid&63 -> cols tx*4..+3 ; ty=tid>>6 -> rows ty*4..+3 (wave-uniform ty)
__global__ __launch_bounds__(256) void k_h1h2(
    int hop,
    const float* __restrict__ W1, const float* __restrict__ b1,
    const float* __restrict__ W2, const float* __restrict__ b2,
    const float* __restrict__ op_noise,
    const int* __restrict__ counts, const int* __restrict__ offsets,
    const int* __restrict__ gidx,
    const float* __restrict__ states, float* __restrict__ part) {
  // XCD-cluster: residue (bid%8) pins a temper class to one XCD's L2
  const int bid = blockIdx.x;
  const int res = bid & 7;
  const int slot = bid >> 3;
  int t, rb;
  if (slot < RBLK) { t = res; rb = slot; }
  else { if (res >= 4) return; t = res + 8; rb = slot - RBLK; }
  const int k = blockIdx.y;

  const int cnt = counts[hop * 16 + t];
  const int r0 = rb * ROWS;
  if (r0 >= cnt) return;
  const int base = offsets[hop * 16 + t] + r0;
  const int rows = min(ROWS, cnt - r0);

  __shared__ __align__(16) float sA[ROWS][HD];      // states rows, then h1 (16 KB)
  __shared__ __align__(16) float sB[2][16][HD];     // weight chunk dbuf (32 KB)

  const int tid = threadIdx.x;
  const int tx = tid & 63;
  const int ty = tid >> 6;

  const float* Wa = W1 + (size_t)(t * KN + k) * HD * HD;
  const float* Wb = W2 + (size_t)(t * KN + k) * HD * HD;

  // stage one contiguous 16x256 weight chunk (16 KB) into sB[b]
#define WSTAGE(gsrc, b)                                                       \
  do {                                                                        \
    const float* g_ = (gsrc);                                                 \
    _Pragma("unroll")                                                         \
    for (int l_ = 0; l_ < 4; ++l_) {                                          \
      int idx_ = tid + l_ * 256;                                              \
      gll16(g_ + idx_ * 4, &sB[b][0][0] + idx_ * 4);                          \
    }                                                                         \
  } while (0)

  // prologue: gather state rows (wave-uniform guard) + W1 chunk 0
#pragma unroll
  for (int l = 0; l < 4; ++l) {
    int r = (tid >> 6) + l * 4;          // uniform per wave
    int c = (tid & 63) << 2;
    if (r < rows)
      gll16(&states[(size_t)gidx[base + r] * HD + c], &sA[r][c]);
  }
  WSTAGE(Wa, 0);

  float acc[4][4];
#pragma unroll
  for (int i = 0; i < 4; ++i)
#pragma unroll
    for (int j = 0; j < 4; ++j) acc[i][j] = 0.f;

#define ECOMP(ch, cur)                                                        \
  do {                                                                        \
    _Pragma("unroll")                                                         \
    for (int k4 = 0; k4 < 4; ++k4) {                                          \
      float4 a4[4];                                                           \
      _Pragma("unroll")                                                       \
      for (int i = 0; i < 4; ++i)                                             \
        a4[i] = *(const float4*)&sA[ty * 4 + i][(ch) * 16 + k4 * 4];          \
      _Pragma("unroll")                                                       \
      for (int u = 0; u < 4; ++u) {                                           \
        float4 bv = *(const float4*)&sB[cur][k4 * 4 + u][tx * 4];             \
        _Pragma("unroll")                                                     \
        for (int i = 0; i < 4; ++i) {                                         \
          float a = ((const float*)&a4[i])[u];                                \
          acc[i][0] = fmaf(a, bv.x, acc[i][0]);                               \
          acc[i][1] = fmaf(a, bv.y, acc[i][1]);                               \
          acc[i][2] = fmaf(a, bv.z, acc[i][2]);                               \
          acc[i][3] = fmaf(a, bv.w, acc[i][3]);                               \
        }                                                                     \
      }                                                                       \
    }                                                                         \
  } while (0)

  // ---- layer 1: 16 chunks of W1; last iteration prefetches W2 chunk 0 ----
#pragma unroll 1
  for (int ch = 0; ch < 15; ++ch) {
    WSTAGE(Wa + (size_t)(ch + 1) * 16 * HD, (ch + 1) & 1);
    VMW4(); BAR();
    ECOMP(ch, ch & 1);
    BAR();
  }
  WSTAGE(Wb, 0);          // W2 chunk 0 -> sB[0]
  VMW4(); BAR();
  ECOMP(15, 1);
  BAR();

  // ---- interlude: h1 = relu(acc + b1) -> sA (syncthreads drains W2c0 + lgkm) ----
  {
    const float* ba = b1 + (t * KN + k) * HD;
    float4 bb = *(const float4*)&ba[tx * 4];
#pragma unroll
    for (int i = 0; i < 4; ++i) {
      float4 v;
      v.x = fmaxf(acc[i][0] + bb.x, 0.f);
      v.y = fmaxf(acc[i][1] + bb.y, 0.f);
      v.z = fmaxf(acc[i][2] + bb.z, 0.f);
      v.w = fmaxf(acc[i][3] + bb.w, 0.f);
      *(float4*)&sA[ty * 4 + i][tx * 4] = v;
      acc[i][0] = 0.f; acc[i][1] = 0.f; acc[i][2] = 0.f; acc[i][3] = 0.f;
    }
  }
  __syncthreads();

  // ---- layer 2: 16 chunks of W2 ----
#pragma unroll 1
  for (int ch = 0; ch < 15; ++ch) {
    WSTAGE(Wb + (size_t)(ch + 1) * 16 * HD, (ch + 1) & 1);
    VMW4(); BAR();
    ECOMP(ch, ch & 1);
    BAR();
  }
  VMW0(); BAR();
  ECOMP(15, 1);

  // ---- epilogue: part_k = wk * relu(acc + b2) ----
  float wkk;
  {
    const float* on = op_noise + (hop * TN + t) * KN;
    float x0 = on[0], x1 = on[1], x2 = on[2];
    float m = fmaxf(fmaxf(x0, x1), x2);
    float e0 = expf(x0 - m), e1 = expf(x1 - m), e2 = expf(x2 - m);
    float ek = (k == 0) ? e0 : (k == 1) ? e1 : e2;
    wkk = ek / (e0 + e1 + e2);
  }
  const float* bbp = b2 + (t * KN + k) * HD;
  float4 bb = *(const float4*)&bbp[tx * 4];
#pragma unroll
  for (int i = 0; i < 4; ++i) {
    int r = ty * 4 + i;
    if (r < rows) {
      float4 o;
      o.x = wkk * fmaxf(acc[i][0] + bb.x, 0.f);
      o.y = wkk * fmaxf(acc[i][1] + bb.y, 0.f);
      o.z = wkk * fmaxf(acc[i][2] + bb.z, 0.f);
      o.w = wkk * fmaxf(acc[i][3] + bb.w, 0.f);
      *(float4*)&part[((size_t)k * BN_ + base + r) * HD + tx * 4] = o;
    }
  }
#undef WSTAGE
#undef ECOMP
}

// ---------------- combine partials + routing head + Gumbel argmax + update ----------------
__global__ __launch_bounds__(256) void k_comb(
    int hop,
    const float* __restrict__ Wr, const float* __restrict__ br,
    const float* __restrict__ route_u,
    const int* __restrict__ counts, const int* __restrict__ offsets,
    const int* __restrict__ gidx,
    const float* __restrict__ part,
    float* __restrict__ states, int* __restrict__ tempers, int* __restrict__ done) {
  const int t  = blockIdx.x % TN;
  const int rb = blockIdx.x / TN;
  const int cnt = counts[hop * 16 + t];
  const int r0 = rb * ROWS;
  if (r0 >= cnt) return;
  const int base = offsets[hop * 16 + t] + r0;
  const int rows = min(ROWS, cnt - r0);

  __shared__ float sO[ROWS][HD + 4];
  __shared__ float sWr[HD * TP1];
  __shared__ float sL[ROWS][16];
  __shared__ int   sN[ROWS];

  const int tid = threadIdx.x;
  if (tid < ROWS && tid < rows) sN[tid] = gidx[base + tid];

#pragma unroll
  for (int l = 0; l < 4; ++l) {
    int idx = tid + l * 256;
    int r = idx >> 6;
    int c = (idx & 63) << 2;
    if (r < rows) {
      size_t p = (size_t)(base + r) * HD + c;
      float4 a = *(const float4*)&part[p];
      float4 b = *(const float4*)&part[(size_t)BN_ * HD + p];
      float4 cc = *(const float4*)&part[(size_t)2 * BN_ * HD + p];
      float4 v = make_float4(a.x + b.x + cc.x, a.y + b.y + cc.y,
                             a.z + b.z + cc.z, a.w + b.w + cc.w);
      *(float4*)&sO[r][c] = v;
      int n = gidx[base + r];
      *(float4*)&states[(size_t)n * HD + c] = v;
    }
  }
  for (int i = tid; i < HD * TP1; i += 256)
    sWr[i] = Wr[(size_t)t * HD * TP1 + i];
  __syncthreads();

  int r = tid >> 4, g = tid & 15;
  if (r < rows && g < TP1) {
    float a = br[t * TP1 + g];
#pragma unroll 8
    for (int f = 0; f < HD; ++f) a = fmaf(sO[r][f], sWr[f * TP1 + g], a);
    float u = route_u[((size_t)hop * BN_ + sN[r]) * TP1 + g];
    float gb = -logf(-logf(u + 1e-9f) + 1e-9f);
    sL[r][g] = a + gb;
  }
  __syncthreads();

  if (tid < rows) {
    float best = sL[tid][0];
    int bj = 0;
#pragma unroll
    for (int gg = 1; gg < TP1; ++gg) {
      float v = sL[tid][gg];
      if (v > best) { best = v; bj = gg; }
    }
    int n = sN[tid];
    tempers[n] = (bj >= TN) ? (TN - 1) : bj;
    if (bj == TN) done[n] = 1;
  }
}

// ---------------- launcher ----------------
extern "C" void kernel_launch(void* const* d_in, const int* in_sizes, int n_in,
                              void* d_out, int out_size, void* d_ws, size_t ws_size,
                              hipStream_t stream) {
  const float* x        = (const float*)d_in[0];
  const int*   init_t   = (const int*)d_in[1];
  const float* op_noise = (const float*)d_in[2];
  const float* route_u  = (const float*)d_in[3];
  const float* W_in     = (const float*)d_in[4];
  const float* b_in     = (const float*)d_in[5];
  const float* W1       = (const float*)d_in[6];
  const float* b1       = (const float*)d_in[7];
  const float* W2       = (const float*)d_in[8];
  const float* b2       = (const float*)d_in[9];
  const float* Wr       = (const float*)d_in[10];
  const float* br       = (const float*)d_in[11];
  const float* W_out    = (const float*)d_in[12];
  const float* b_out    = (const float*)d_in[13];
  float* out = (float*)d_out;

  float* states = (float*)d_ws;
  float* part   = states + (size_t)BN_ * HD;                 // [KN][BN_][HD]
  int* ib      = (int*)(part + (size_t)KN * BN_ * HD);
  int* tempers = ib;
  int* done    = ib + BN_;
  int* counts  = ib + 2 * BN_;
  int* offsets = counts + NHOPS * 16;
  int* gidx    = offsets + NHOPS * 16;

  k_init<<<(BN_ + 255) / 256, 256, 0, stream>>>(init_t, tempers, done);

  k_gemm_bias<<<dim3(BN_ / 32, HD / 64), 256, 0, stream>>>(
      x, W_in, b_in, states, BN_, HD, INDIM);

  for (int hop = 0; hop < NHOPS; ++hop) {
    k_prep<<<1, 1024, 0, stream>>>(hop, tempers, done, counts, offsets, gidx);
    k_h1h2<<<dim3(8 * 2 * RBLK, KN), 256, 0, stream>>>(
        hop, W1, b1, W2, b2, op_noise, counts, offsets, gidx, states, part);
    k_comb<<<TN * RBLK, 256, 0, stream>>>(
        hop, Wr, br, route_u, counts, offsets, gidx, part, states, tempers, done);
  }

  k_gemm_bias<<<dim3(BN_ / 32, OD / 64), 256, 0, stream>>>(
      states, W_out, b_out, out, BN_, OD, HD);
}

// Round 4
// 286.227 us; speedup vs baseline: 2.9934x; 1.2423x over previous
//
#include <hip/hip_runtime.h>
#include <math.h>

#define BN_   2048
#define INDIM 1024
#define HD    256
#define OD    512
#define TN    12
#define KN    3
#define NHOPS 4
#define TP1   13

#define ROWS  16
#define RBLK  (BN_ / ROWS)   // 128

// async global -> LDS, 16B per lane (LDS dest linear in tid)
__device__ __forceinline__ void gll16(const float* g, float* l) {
  __builtin_amdgcn_global_load_lds(
      (const __attribute__((address_space(1))) void*)g,
      (__attribute__((address_space(3))) void*)l, 16, 0, 0);
}

__device__ __forceinline__ float4 ld4(const float* p) { return *(const float4*)p; }

__device__ __forceinline__ void fma4(float4& c, float a, const float4 b) {
  c.x = fmaf(a, b.x, c.x); c.y = fmaf(a, b.y, c.y);
  c.z = fmaf(a, b.z, c.z); c.w = fmaf(a, b.w, c.w);
}
__device__ __forceinline__ void add4(float4& c, const float4 b) {
  c.x += b.x; c.y += b.y; c.z += b.z; c.w += b.w;
}

// ---- barrier-free K loop: acc[16] (+= A[16rows x k-slice] @ W[k-slice x 4cols])
// SA: LDS float base; ASTR: row stride (floats); WROW0: &W[ks*WS + colbase] (global);
// WS: W row stride (floats); NK4: #4k-steps; KS0: slice start (index into SA rows)
#define KLOOP(SA, ASTR, WROW0, WS, NK4, KS0)                                   \
  do {                                                                         \
    const float* wp_ = (WROW0);                                                \
    float4 wA0 = ld4(wp_), wA1 = ld4(wp_ + (WS)), wA2 = ld4(wp_ + 2 * (WS)),   \
           wA3 = ld4(wp_ + 3 * (WS));                                          \
    _Pragma("unroll 1")                                                        \
    for (int k4_ = 0; k4_ < (NK4) - 1; ++k4_) {                                \
      const float* wn_ = wp_ + 4 * (WS);                                       \
      float4 wB0 = ld4(wn_), wB1 = ld4(wn_ + (WS)), wB2 = ld4(wn_ + 2 * (WS)), \
             wB3 = ld4(wn_ + 3 * (WS));                                        \
      const int kk_ = (KS0) + k4_ * 4;                                         \
      _Pragma("unroll")                                                        \
      for (int r_ = 0; r_ < 16; ++r_) {                                        \
        float4 av = *(const float4*)((SA) + r_ * (ASTR) + kk_);                \
        fma4(acc[r_], av.x, wA0); fma4(acc[r_], av.y, wA1);                    \
        fma4(acc[r_], av.z, wA2); fma4(acc[r_], av.w, wA3);                    \
      }                                                                        \
      wA0 = wB0; wA1 = wB1; wA2 = wB2; wA3 = wB3; wp_ = wn_;                   \
    }                                                                          \
    const int kk_ = (KS0) + ((NK4) - 1) * 4;                                   \
    _Pragma("unroll")                                                          \
    for (int r_ = 0; r_ < 16; ++r_) {                                          \
      float4 av = *(const float4*)((SA) + r_ * (ASTR) + kk_);                  \
      fma4(acc[r_], av.x, wA0); fma4(acc[r_], av.y, wA1);                      \
      fma4(acc[r_], av.z, wA2); fma4(acc[r_], av.w, wA3);                      \
    }                                                                          \
  } while (0)

// ---- deterministic 4-wave k-slice reduction; wave 0 ends with full sum ----
#define REDUCE4()                                                              \
  do {                                                                         \
    __syncthreads();                                                           \
    if (w == 1) { _Pragma("unroll") for (int r = 0; r < 16; ++r) pbA[r][tx] = acc[r]; } \
    else if (w == 3) { _Pragma("unroll") for (int r = 0; r < 16; ++r) pbB[r][tx] = acc[r]; } \
    __syncthreads();                                                           \
    if (w == 0) { _Pragma("unroll") for (int r = 0; r < 16; ++r) add4(acc[r], pbA[r][tx]); } \
    else if (w == 2) { _Pragma("unroll") for (int r = 0; r < 16; ++r) add4(acc[r], pbB[r][tx]); } \
    __syncthreads();                                                           \
    if (w == 2) { _Pragma("unroll") for (int r = 0; r < 16; ++r) pbA[r][tx] = acc[r]; } \
    __syncthreads();                                                           \
    if (w == 0) { _Pragma("unroll") for (int r = 0; r < 16; ++r) add4(acc[r], pbA[r][tx]); } \
  } while (0)

// ---------------- init ----------------
__global__ __launch_bounds__(256) void k_init(const int* __restrict__ init_t,
                                              int* __restrict__ tempers,
                                              int* __restrict__ done) {
  int n = blockIdx.x * 256 + threadIdx.x;
  if (n < BN_) { tempers[n] = init_t[n]; done[n] = 0; }
}

// ---------------- per-hop grouping ----------------
__global__ __launch_bounds__(1024) void k_prep(int hop,
                                               const int* __restrict__ tempers,
                                               const int* __restrict__ done,
                                               int* __restrict__ counts,
                                               int* __restrict__ offsets,
                                               int* __restrict__ gidx) {
  __shared__ int cnt[TN];
  __shared__ int offs[TN];
  __shared__ int cur[TN];
  int tid = threadIdx.x;
  if (tid < TN) cnt[tid] = 0;
  __syncthreads();
  for (int n = tid; n < BN_; n += 1024)
    if (!done[n]) atomicAdd(&cnt[tempers[n]], 1);
  __syncthreads();
  if (tid == 0) {
    int run = 0;
    for (int t = 0; t < TN; ++t) { offs[t] = run; run += cnt[t]; }
  }
  __syncthreads();
  if (tid < TN) {
    counts[hop * 16 + tid]  = cnt[tid];
    offsets[hop * 16 + tid] = offs[tid];
    cur[tid] = offs[tid];
  }
  __syncthreads();
  for (int n = tid; n < BN_; n += 1024)
    if (!done[n]) { int p = atomicAdd(&cur[tempers[n]], 1); gidx[p] = n; }
}

// ---------------- gemm_in partial: pp[kh] = x[:, kh*512:+512] @ W_in[kh*512:+512, :] ----------------
__global__ __launch_bounds__(256) void k_gemm_in(const float* __restrict__ A,
                                                 const float* __restrict__ W,
                                                 float* __restrict__ pp) {
  const int bm = blockIdx.x * ROWS;
  const int kh = blockIdx.y;
  __shared__ float  sA[ROWS][512];     // 32KB
  __shared__ float4 pbA[16][64];       // 16KB
  __shared__ float4 pbB[16][64];       // 16KB
  const int tid = threadIdx.x;
  const int tx = tid & 63;
  const int w = tid >> 6;

#pragma unroll
  for (int l = 0; l < 8; ++l) {
    int idx = tid + l * 256;
    int r = idx >> 7;                  // wave-uniform
    int c = (idx & 127) << 2;
    gll16(&A[(size_t)(bm + r) * INDIM + kh * 512 + c], &sA[r][c]);
  }
  __syncthreads();

  float4 acc[16];
#pragma unroll
  for (int r = 0; r < 16; ++r) acc[r] = make_float4(0.f, 0.f, 0.f, 0.f);

  const int ks = w * 128;
  KLOOP(&sA[0][0], 512, W + (size_t)(kh * 512 + ks) * HD + tx * 4, HD, 32, ks);
  REDUCE4();

  if (w == 0) {
#pragma unroll
    for (int r = 0; r < 16; ++r)
      *(float4*)&pp[((size_t)kh * BN_ + bm + r) * HD + tx * 4] = acc[r];
  }
}

// ---------------- combine gemm_in partials + bias ----------------
__global__ __launch_bounds__(256) void k_cin(const float* __restrict__ pp,
                                             const float* __restrict__ bias,
                                             float* __restrict__ states) {
  int idx = blockIdx.x * 256 + threadIdx.x;     // float4 index
  int c = (idx & 63) << 2;
  float4 a = ld4(&pp[(size_t)idx * 4]);
  float4 b = ld4(&pp[(size_t)BN_ * HD + (size_t)idx * 4]);
  float4 bv = ld4(&bias[c]);
  float4 o = make_float4(a.x + b.x + bv.x, a.y + b.y + bv.y,
                         a.z + b.z + bv.z, a.w + b.w + bv.w);
  *(float4*)&states[(size_t)idx * 4] = o;
}

// ---------------- gemm_out: out = states @ W_out + b_out (N-split grid) ----------------
__global__ __launch_bounds__(256) void k_gemm_out(const float* __restrict__ A,
                                                  const float* __restrict__ W,
                                                  const float* __restrict__ bias,
                                                  float* __restrict__ C) {
  const int bm = blockIdx.x * ROWS;
  const int cb = blockIdx.y * 256;
  __shared__ float  sA[ROWS][HD];      // 16KB
  __shared__ float4 pbA[16][64];
  __shared__ float4 pbB[16][64];
  const int tid = threadIdx.x;
  const int tx = tid & 63;
  const int w = tid >> 6;

#pragma unroll
  for (int l = 0; l < 4; ++l) {
    int r = w + l * 4;
    int c = tx << 2;
    gll16(&A[(size_t)(bm + r) * HD + c], &sA[r][c]);
  }
  __syncthreads();

  float4 acc[16];
#pragma unroll
  for (int r = 0; r < 16; ++r) acc[r] = make_float4(0.f, 0.f, 0.f, 0.f);

  const int ks = w * 64;
  KLOOP(&sA[0][0], HD, W + (size_t)ks * OD + cb + tx * 4, OD, 16, ks);
  REDUCE4();

  if (w == 0) {
    float4 bv = ld4(&bias[cb + tx * 4]);
#pragma unroll
    for (int r = 0; r < 16; ++r) {
      float4 o = make_float4(acc[r].x + bv.x, acc[r].y + bv.y,
                             acc[r].z + bv.z, acc[r].w + bv.w);
      *(float4*)&C[(size_t)(bm + r) * OD + cb + tx * 4] = o;
    }
  }
}

// ---------------- fused expert: part_k = wk*relu(relu(S@W1+b1)@W2+b2) ----------------
__global__ __launch_bounds__(256) void k_h1h2(
    int hop,
    const float* __restrict__ W1, const float* __restrict__ b1,
    const float* __restrict__ W2, const float* __restrict__ b2,
    const float* __restrict__ op_noise,
    const int* __restrict__ counts, const int* __restrict__ offsets,
    const int* __restrict__ gidx,
    const float* __restrict__ states, float* __restrict__ part) {
  // XCD-cluster: residue (bid%8) pins a temper class to one XCD's L2
  const int bid = blockIdx.x;
  const int res = bid & 7;
  const int slot = bid >> 3;
  int t, rb;
  if (slot < RBLK) { t = res; rb = slot; }
  else { if (res >= 4) return; t = res + 8; rb = slot - RBLK; }
  const int k = blockIdx.y;

  const int cnt = counts[hop * 16 + t];
  const int r0 = rb * ROWS;
  if (r0 >= cnt) return;
  const int base = offsets[hop * 16 + t] + r0;
  const int rows = min(ROWS, cnt - r0);

  __shared__ float  sA[ROWS][HD];      // 16KB: states rows
  __shared__ float4 pbA[16][64];       // 16KB: reduction ping
  __shared__ float4 pbB[16][64];       // 16KB: reduction pong / h1 (sH)
  const int tid = threadIdx.x;
  const int tx = tid & 63;
  const int w = tid >> 6;

  // gather active rows (wave-uniform r; guarded for tail)
#pragma unroll
  for (int l = 0; l < 4; ++l) {
    int r = w + l * 4;
    int c = tx << 2;
    if (r < rows)
      gll16(&states[(size_t)gidx[base + r] * HD + c], &sA[r][c]);
  }
  __syncthreads();

  const float* Wa = W1 + (size_t)(t * KN + k) * HD * HD;
  const float* Wb = W2 + (size_t)(t * KN + k) * HD * HD;
  const int ks = w * 64;

  float4 acc[16];
#pragma unroll
  for (int r = 0; r < 16; ++r) acc[r] = make_float4(0.f, 0.f, 0.f, 0.f);

  // ---- layer 1 ----
  KLOOP(&sA[0][0], HD, Wa + (size_t)ks * HD + tx * 4, HD, 16, ks);
  REDUCE4();

  float* sH = (float*)pbB;
  if (w == 0) {
    float4 bv = ld4(&b1[(t * KN + k) * HD + tx * 4]);
#pragma unroll
    for (int r = 0; r < 16; ++r) {
      float4 h;
      h.x = fmaxf(acc[r].x + bv.x, 0.f);
      h.y = fmaxf(acc[r].y + bv.y, 0.f);
      h.z = fmaxf(acc[r].z + bv.z, 0.f);
      h.w = fmaxf(acc[r].w + bv.w, 0.f);
      *(float4*)&sH[r * HD + tx * 4] = h;
    }
  }
  __syncthreads();

  // ---- layer 2 ----
#pragma unroll
  for (int r = 0; r < 16; ++r) acc[r] = make_float4(0.f, 0.f, 0.f, 0.f);
  KLOOP(sH, HD, Wb + (size_t)ks * HD + tx * 4, HD, 16, ks);
  REDUCE4();

  if (w == 0) {
    float wkk;
    {
      const float* on = op_noise + (hop * TN + t) * KN;
      float x0 = on[0], x1 = on[1], x2 = on[2];
      float m = fmaxf(fmaxf(x0, x1), x2);
      float e0 = expf(x0 - m), e1 = expf(x1 - m), e2 = expf(x2 - m);
      float ek = (k == 0) ? e0 : (k == 1) ? e1 : e2;
      wkk = ek / (e0 + e1 + e2);
    }
    float4 bv = ld4(&b2[(t * KN + k) * HD + tx * 4]);
#pragma unroll
    for (int r = 0; r < 16; ++r) {
      if (r < rows) {
        float4 o;
        o.x = wkk * fmaxf(acc[r].x + bv.x, 0.f);
        o.y = wkk * fmaxf(acc[r].y + bv.y, 0.f);
        o.z = wkk * fmaxf(acc[r].z + bv.z, 0.f);
        o.w = wkk * fmaxf(acc[r].w + bv.w, 0.f);
        *(float4*)&part[((size_t)k * BN_ + base + r) * HD + tx * 4] = o;
      }
    }
  }
}

// ---------------- combine partials + routing head + Gumbel argmax + update ----------------
__global__ __launch_bounds__(256) void k_comb(
    int hop,
    const float* __restrict__ Wr, const float* __restrict__ br,
    const float* __restrict__ route_u,
    const int* __restrict__ counts, const int* __restrict__ offsets,
    const int* __restrict__ gidx,
    const float* __restrict__ part,
    float* __restrict__ states, int* __restrict__ tempers, int* __restrict__ done) {
  const int t  = blockIdx.x % TN;
  const int rb = blockIdx.x / TN;
  const int cnt = counts[hop * 16 + t];
  const int r0 = rb * ROWS;
  if (r0 >= cnt) return;
  const int base = offsets[hop * 16 + t] + r0;
  const int rows = min(ROWS, cnt - r0);

  __shared__ float sO[ROWS][HD + 4];
  __shared__ float sWr[HD * TP1];
  __shared__ float sL[ROWS][16];
  __shared__ int   sN[ROWS];

  const int tid = threadIdx.x;
  if (tid < ROWS && tid < rows) sN[tid] = gidx[base + tid];

#pragma unroll
  for (int l = 0; l < 4; ++l) {
    int idx = tid + l * 256;
    int r = idx >> 6;
    int c = (idx & 63) << 2;
    if (r < rows) {
      size_t p = (size_t)(base + r) * HD + c;
      float4 a = ld4(&part[p]);
      float4 b = ld4(&part[(size_t)BN_ * HD + p]);
      float4 cc = ld4(&part[(size_t)2 * BN_ * HD + p]);
      float4 v = make_float4(a.x + b.x + cc.x, a.y + b.y + cc.y,
                             a.z + b.z + cc.z, a.w + b.w + cc.w);
      *(float4*)&sO[r][c] = v;
      int n = gidx[base + r];
      *(float4*)&states[(size_t)n * HD + c] = v;
    }
  }
  for (int i = tid; i < HD * TP1; i += 256)
    sWr[i] = Wr[(size_t)t * HD * TP1 + i];
  __syncthreads();

  int r = tid >> 4, g = tid & 15;
  if (r < rows && g < TP1) {
    float a = br[t * TP1 + g];
#pragma unroll 8
    for (int f = 0; f < HD; ++f) a = fmaf(sO[r][f], sWr[f * TP1 + g], a);
    float u = route_u[((size_t)hop * BN_ + sN[r]) * TP1 + g];
    float gb = -logf(-logf(u + 1e-9f) + 1e-9f);
    sL[r][g] = a + gb;
  }
  __syncthreads();

  if (tid < rows) {
    float best = sL[tid][0];
    int bj = 0;
#pragma unroll
    for (int gg = 1; gg < TP1; ++gg) {
      float v = sL[tid][gg];
      if (v > best) { best = v; bj = gg; }
    }
    int n = sN[tid];
    tempers[n] = (bj >= TN) ? (TN - 1) : bj;
    if (bj == TN) done[n] = 1;
  }
}

// ---------------- launcher ----------------
extern "C" void kernel_launch(void* const* d_in, const int* in_sizes, int n_in,
                              void* d_out, int out_size, void* d_ws, size_t ws_size,
                              hipStream_t stream) {
  const float* x        = (const float*)d_in[0];
  const int*   init_t   = (const int*)d_in[1];
  const float* op_noise = (const float*)d_in[2];
  const float* route_u  = (const float*)d_in[3];
  const float* W_in     = (const float*)d_in[4];
  const float* b_in     = (const float*)d_in[5];
  const float* W1       = (const float*)d_in[6];
  const float* b1       = (const float*)d_in[7];
  const float* W2       = (const float*)d_in[8];
  const float* b2       = (const float*)d_in[9];
  const float* Wr       = (const float*)d_in[10];
  const float* br       = (const float*)d_in[11];
  const float* W_out    = (const float*)d_in[12];
  const float* b_out    = (const float*)d_in[13];
  float* out = (float*)d_out;

  float* states = (float*)d_ws;
  float* part   = states + (size_t)BN_ * HD;                 // [KN][BN_][HD] (6MB)
  float* pp     = part;                                      // gemm_in partials alias (4MB)
  int* ib      = (int*)(part + (size_t)KN * BN_ * HD);
  int* tempers = ib;
  int* done    = ib + BN_;
  int* counts  = ib + 2 * BN_;
  int* offsets = counts + NHOPS * 16;
  int* gidx    = offsets + NHOPS * 16;

  k_init<<<(BN_ + 255) / 256, 256, 0, stream>>>(init_t, tempers, done);

  k_gemm_in<<<dim3(RBLK, 2), 256, 0, stream>>>(x, W_in, pp);
  k_cin<<<(BN_ * HD / 4) / 256, 256, 0, stream>>>(pp, b_in, states);

  for (int hop = 0; hop < NHOPS; ++hop) {
    k_prep<<<1, 1024, 0, stream>>>(hop, tempers, done, counts, offsets, gidx);
    k_h1h2<<<dim3(8 * 2 * RBLK, KN), 256, 0, stream>>>(
        hop, W1, b1, W2, b2, op_noise, counts, offsets, gidx, states, part);
    k_comb<<<TN * RBLK, 256, 0, stream>>>(
        hop, Wr, br, route_u, counts, offsets, gidx, part, states, tempers, done);
  }

  k_gemm_out<<<dim3(RBLK, OD / 256), 256, 0, stream>>>(states, W_out, b_out, out);
}